// Round 1
// 352.732 us; speedup vs baseline: 1.0037x; 1.0037x over previous
//
#include <hip/hip_runtime.h>
#include <math.h>

// SPP mix (max + mean), levels {1,2,4}, input (32,64,64,512) fp32 channels-last.
// v2: latency-bound fix. Previous version ran 8 waves/CU (512 blocks x 256 thr)
// with ~8 outstanding loads/wave -> ~0.7 TB/s effective (Little's law), ~350us.
// Now: 512 blocks x 1024 threads = 32 waves/CU (launch_bounds forces VGPR<=64
// so 2 blocks/CU co-reside). Kernel 1 reads input once, reduces 16x16 windows
// via LDS tree across 8 row-slices, writes bin partials + level-4 outputs.
// Kernel 2 (256 blocks, was 16) computes levels 2 and 1 from bin partials.

#define B_ 32
#define HW_ 64
#define C_ 512
#define CVEC 128  // C/4 float4 channel-groups

__device__ __forceinline__ float4 f4max(float4 a, float4 b) {
    return make_float4(fmaxf(a.x, b.x), fmaxf(a.y, b.y),
                       fmaxf(a.z, b.z), fmaxf(a.w, b.w));
}
__device__ __forceinline__ float4 f4add(float4 a, float4 b) {
    return make_float4(a.x + b.x, a.y + b.y, a.z + b.z, a.w + b.w);
}
__device__ __forceinline__ float4 f4mix(float4 m, float4 s, float inv) {
    return make_float4(m.x + s.x * inv, m.y + s.y * inv,
                       m.z + s.z * inv, m.w + s.w * inv);
}

// Kernel 1: one block per (b, bin), bin = br*4+bc over 4x4 grid of 16x16 windows.
// 1024 threads = 128 channel-groups x 8 row-slices (2 rows x 16 cols each).
// Writes per-bin max/sum partials AND the level-4 outputs.
__global__ __launch_bounds__(1024, 8) void spp_bins_kernel(
    const float4* __restrict__ x,
    float4* __restrict__ maxbuf,
    float4* __restrict__ sumbuf,
    float4* __restrict__ out)
{
    const int blk   = blockIdx.x;      // [0, B_*16)
    const int b     = blk >> 4;
    const int bin   = blk & 15;
    const int br    = bin >> 2;
    const int bc    = bin & 3;
    const int tid   = threadIdx.x;
    const int cg    = tid & (CVEC - 1);
    const int slice = tid >> 7;        // 0..7 -> rows {2*slice, 2*slice+1}

    // float4 index of x[b][br*16 + slice*2][bc*16][4*cg]
    const int base =
        ((b * HW_ + br * 16 + slice * 2) * HW_ + bc * 16) * CVEC + cg;
    const float4* p = x + base;

    float4 mx = make_float4(-INFINITY, -INFINITY, -INFINITY, -INFINITY);
    float4 sm = make_float4(0.f, 0.f, 0.f, 0.f);

    // 2 rows x 16 cols per thread; unroll 8 keeps ~8 loads in flight
    // without blowing the 64-VGPR budget (needed for 2 blocks/CU).
    #pragma unroll 8
    for (int k = 0; k < 32; ++k) {
        const int r = k >> 4;          // 0..1 (row within slice)
        const int j = k & 15;          // 0..15 (col within window)
        const float4 v = p[(r * HW_ + j) * CVEC];
        mx = f4max(mx, v);
        sm = f4add(sm, v);
    }

    __shared__ float4 smax[8][CVEC];
    __shared__ float4 ssum[8][CVEC];
    smax[slice][cg] = mx;
    ssum[slice][cg] = sm;
    __syncthreads();

    #pragma unroll
    for (int off = 4; off >= 1; off >>= 1) {
        if (slice < off) {
            mx = f4max(mx, smax[slice + off][cg]);
            sm = f4add(sm, ssum[slice + off][cg]);
            if (off > 1) { smax[slice][cg] = mx; ssum[slice][cg] = sm; }
        }
        __syncthreads();
    }

    if (slice == 0) {
        const int o = (b * 16 + bin) * CVEC + cg;
        maxbuf[o] = mx;
        sumbuf[o] = sm;
        // level 4 output: offset 5C (=5*CVEC float4), index (bc*4+br)*C + c
        const int row = b * (21 * CVEC);
        out[row + 5 * CVEC + (bc * 4 + br) * CVEC + cg] =
            f4mix(mx, sm, 1.0f / 256.0f);
    }
}

// Kernel 2: levels 2 and 1. One block per (b, 16-channel-group chunk):
// grid = 32*8 = 256 blocks, 256 threads = 16 bins x 16 channel-groups.
// Each thread loads its (bin, cg) partial (2 x 16B); LDS reduces bins.
__global__ __launch_bounds__(256) void spp_l12_kernel(
    const float4* __restrict__ maxbuf,
    const float4* __restrict__ sumbuf,
    float4* __restrict__ out)
{
    const int b   = blockIdx.x >> 3;
    const int cgc = blockIdx.x & 7;     // channel chunk, 16 cgs each
    const int tid = threadIdx.x;
    const int bin = tid >> 4;           // 0..15
    const int cgi = tid & 15;           // 0..15
    const int cg  = cgc * 16 + cgi;

    __shared__ float4 sm_[16][16];
    __shared__ float4 ss_[16][16];
    __shared__ float4 sm2[4][16];
    __shared__ float4 ss2[4][16];

    const int o = (b * 16 + bin) * CVEC + cg;
    sm_[bin][cgi] = maxbuf[o];
    ss_[bin][cgi] = sumbuf[o];
    __syncthreads();

    const int row = b * (21 * CVEC);

    // level 2 (offset C): combine 2x2 bins, mean /1024. 64 active threads.
    if (tid < 64) {
        const int l2 = tid >> 4;        // pr*2 + pc
        const int pr = l2 >> 1, pc = l2 & 1;
        const int b00 = (2 * pr) * 4 + (2 * pc);
        float4 mm = f4max(f4max(sm_[b00][cgi], sm_[b00 + 1][cgi]),
                          f4max(sm_[b00 + 4][cgi], sm_[b00 + 5][cgi]));
        float4 ss = f4add(f4add(ss_[b00][cgi], ss_[b00 + 1][cgi]),
                          f4add(ss_[b00 + 4][cgi], ss_[b00 + 5][cgi]));
        sm2[l2][cgi] = mm;
        ss2[l2][cgi] = ss;
        out[row + CVEC + (pc * 2 + pr) * CVEC + cg] =
            f4mix(mm, ss, 1.0f / 1024.0f);
    }
    __syncthreads();

    // level 1 (offset 0): combine all, mean /4096. 16 active threads.
    if (tid < 16) {
        float4 mm = f4max(f4max(sm2[0][tid], sm2[1][tid]),
                          f4max(sm2[2][tid], sm2[3][tid]));
        float4 ss = f4add(f4add(ss2[0][tid], ss2[1][tid]),
                          f4add(ss2[2][tid], ss2[3][tid]));
        out[row + cgc * 16 + tid] = f4mix(mm, ss, 1.0f / 4096.0f);
    }
}

extern "C" void kernel_launch(void* const* d_in, const int* in_sizes, int n_in,
                              void* d_out, int out_size, void* d_ws, size_t ws_size,
                              hipStream_t stream) {
    const float4* x = (const float4*)d_in[0];
    float* ws = (float*)d_ws;
    float4* maxbuf = (float4*)ws;                        // 32*16*512 floats
    float4* sumbuf = (float4*)(ws + B_ * 16 * C_);       // 32*16*512 floats
    float4* out = (float4*)d_out;

    spp_bins_kernel<<<B_ * 16, 1024, 0, stream>>>(x, maxbuf, sumbuf, out);
    spp_l12_kernel<<<B_ * 8, 256, 0, stream>>>(maxbuf, sumbuf, out);
}